// Round 8
// baseline (71.814 us; speedup 1.0000x reference)
//
#include <hip/hip_runtime.h>
#include <cstdint>

// Problem constants (from reference)
#define B 64
#define P 5000
#define G 300
#define C 20
#define SCALE_F 512.0f
#define IOU_TH 0.5f
#define NSPLIT 8                              // worker chunks per image
#define PCHUNK ((P + NSPLIT - 1) / NSPLIT)    // 625
#define NTA 512
#define SPT ((PCHUNK + NTA - 1) / NTA)        // 2 pred slots per thread
#define NCHUNK ((G + 63) / 64)                // 5 target wave-chunks
#define SENT 0x7FFFFFFF
#define TAG 0x4BCD0000u                       // claim tag: distinct-byte hi16, not a
                                              // byte-repeat pattern; != common poisons
#define NOCLAIM 0xFFFFu                       // claim16 for "no claimant" (pred idx < 5000)

// Match numpy float32 semantics exactly: no FMA contraction (hipcc defaults
// to contract=fast). Division stays IEEE (no fast-math).
#pragma clang fp contract(off)

// ---------------------------------------------------------------------------
// Round-8: ONE plain dispatch. R3 vs R7 (radically different match bodies,
// identical 70.3/70.4us) proved match is at its ~6us work floor and the
// residual is dispatch overhead (~10us/launch, calibrated on R5/R6). Coop
// launch is disqualified (R6: +30us). So resolve is fused via a fence-free
// handshake:
//  * grid (NSPLIT+1, B): s<8 = R7 worker body; s==8 = per-image resolver.
//  * workers publish chunk-claims as SELF-VALIDATING tagged atomics:
//    atomicExch(slice[b][s][t], TAG | claim16). Each element is
//    independently validated by the resolver (spin until hi16==TAG), so no
//    threadfence / release-acquire is needed (atomics are device-coherent;
//    R0 lesson: fences on gfx950 = L2 flush storms).
//  * resolver owns the ENTIRE corr field: dense corr=0 pass first (overlaps
//    worker compute), __syncthreads, poll+min the 8 slices, flip winners.
//    Workers write only score/cls dwords -> no same-address cross-XCD
//    plain-store pair anywhere (the R1-R7 0-then-1 overwrite is gone).
//  * deadlock-free spin: launch_bounds(512,4) + 8KB LDS -> >=2 blocks/CU
//    capacity = 512+ resident of 576 total; only 64 blocks ever spin, and
//    all worker blocks are always schedulable.
// Worker semantics unchanged from R7 (verified 70.4, absmax 0): ballot-rank
// STABLE target class-sort (chunk-major + lane order == original index
// order -> jnp.argmax first-occurrence tie-break), natural-order coalesced
// pred pass, divergent bucket loop, firstp in sorted-target space
// (deterministic per image -> consistent across blocks), atomicMin claims,
// IoU op-for-op identical (contract off, IEEE div).
// ---------------------------------------------------------------------------
__global__ __launch_bounds__(NTA, 4) void fused_kernel(
    const float* __restrict__ preds,      // [B,P,6]
    const float* __restrict__ labels,     // [B,G,5]
    unsigned int* __restrict__ slices,    // [B,NSPLIT,G] tagged claims
    float* __restrict__ out_stats,        // [B,P,3]
    float* __restrict__ out_tcls)         // [B,G]
{
    const int s = blockIdx.x;
    const int b = blockIdx.y;
    const int tid = threadIdx.x;

    // ================= resolver block (s == NSPLIT) =================
    if (s == NSPLIT) {
        // dense corr=0 (sole owner of the corr dword; overlaps workers)
        for (int i = tid; i < P; i += NTA)
            out_stats[((size_t)b * P + i) * 3] = 0.0f;
        __syncthreads();                   // corr=0 done before any flip
        if (tid < G) {
            unsigned m = NOCLAIM;
            for (int s2 = 0; s2 < NSPLIT; ++s2) {
                unsigned int* p = &slices[((size_t)b * NSPLIT + s2) * G + tid];
                unsigned v;
                do { v = atomicOr(p, 0u); } while ((v >> 16) != (TAG >> 16));
                unsigned c16 = v & 0xFFFFu;
                m = c16 < m ? c16 : m;     // claim16 order == pred order
            }
            // a pred claims only its own argmax target -> flips never collide
            if (m != NOCLAIM)
                out_stats[((size_t)b * P + m) * 3] = 1.0f;
        }
        return;
    }

    // ================= worker blocks (R7 body) =================
    const int lane = tid & 63;
    const int w = tid >> 6;

    __shared__ float4 sb[G];              // class-sorted scaled target boxes
    __shared__ float  sa[G];              // areas (sorted order)
    __shared__ int    chist[NCHUNK][C];   // per-wave-chunk target class counts
    __shared__ int    so[C + 1];          // target bucket offsets
    __shared__ int    firstp[G];          // chunk-local lowest claimant (sorted space)

    const float* lab = labels + (size_t)b * G * 5;
    const float* prd = preds + (size_t)b * P * 6;
    const int pbase = s * PCHUNK;
    const int pend = (pbase + PCHUNK < P) ? pbase + PCHUNK : P;

    // ---- P1: target load (registers) + ballot histogram + inits ----
    if (tid < G) firstp[tid] = SENT;

    float tx1 = 0, ty1 = 0, tx2 = 0, ty2 = 0;
    int tc = -1;
    unsigned long long tmask = 0;
    if (tid < NCHUNK * 64) {              // waves 0..4 fully active for ballot
        if (tid < G) {
            tx1 = lab[tid * 5 + 0];
            ty1 = lab[tid * 5 + 1];
            tx2 = lab[tid * 5 + 2];
            ty2 = lab[tid * 5 + 3];
            float cf = lab[tid * 5 + 4];
            tc = (int)cf;
            if (s == 0) out_tcls[(size_t)b * G + tid] = cf;
        }
        #pragma unroll
        for (int cc = 0; cc < C; ++cc) {
            unsigned long long m = __ballot(tc == cc);
            if (tc == cc) tmask = m;                       // keep for scatter
            if (lane == cc) chist[w][cc] = __popcll(m);    // race-free write
        }
    }
    __syncthreads();

    // ---- P2: wave-0 scans: chunk-exclusive per class, then class bases ----
    if (tid < 64) {
        int run = 0;
        if (lane < C) {
            #pragma unroll
            for (int u = 0; u < NCHUNK; ++u) {
                int t = chist[u][lane]; chist[u][lane] = run; run += t;
            }
        }
        int v = (lane < C) ? run : 0;      // inclusive scan over class lanes
        #pragma unroll
        for (int d = 1; d < 32; d <<= 1) {
            int o = __shfl_up(v, d);
            if (lane >= d) v += o;
        }
        if (lane < C) so[lane + 1] = v;
        if (lane == 0) so[0] = 0;
    }
    __syncthreads();

    // ---- P3: stable target scatter from registers (sorted space) ----
    if (tid < G) {
        int rank = chist[w][tc] + __popcll(tmask & ((1ull << lane) - 1));
        int pos = so[tc] + rank;           // stable: chunk-major + lane order
        float x1 = tx1 * SCALE_F;          // *512 exact (pow2)
        float y1 = ty1 * SCALE_F;
        float x2 = tx2 * SCALE_F;
        float y2 = ty2 * SCALE_F;
        sb[pos] = make_float4(x1, y1, x2, y2);
        sa[pos] = (x2 - x1) * (y2 - y1);
    }
    __syncthreads();

    // ---- P4: match, natural pred order (coalesced); score/cls only ----
    #pragma unroll
    for (int k = 0; k < SPT; ++k) {
        int p = pbase + k * NTA + tid;
        if (p >= pend) continue;
        const float* pr = prd + (size_t)p * 6;
        float2 q0 = *reinterpret_cast<const float2*>(pr);       // x1,y1
        float2 q1 = *reinterpret_cast<const float2*>(pr + 2);   // x2,y2
        float2 q2 = *reinterpret_cast<const float2*>(pr + 4);   // score,cls
        float px1 = q0.x * SCALE_F;
        float py1 = q0.y * SCALE_F;
        float px2 = q1.x * SCALE_F;
        float py2 = q1.y * SCALE_F;
        float score = q2.x;
        int c = (int)q2.y;
        float parea = (px2 - px1) * (py2 - py1);

        size_t ip3 = ((size_t)b * P + p) * 3;
        out_stats[ip3 + 1] = score;        // corr dword owned by resolver
        out_stats[ip3 + 2] = q2.y;

        int lo = so[c], hi = so[c + 1];    // per-lane bounds (divergent loop)
        float best = -1.0f;
        int bi = -1;
        // sorted order within class == original order; strict > keeps FIRST max
        for (int j = lo; j < hi; ++j) {
            float4 tb = sb[j];
            float lx = fmaxf(px1, tb.x);
            float ly = fmaxf(py1, tb.y);
            float rx = fminf(px2, tb.z);
            float ry = fminf(py2, tb.w);
            float wd = fmaxf(rx - lx, 0.0f);
            float ht = fmaxf(ry - ly, 0.0f);
            float inter = wd * ht;
            float uni = (parea + sa[j]) - inter;   // reference assoc order
            float iou = inter / uni;               // IEEE div
            if (iou > best) { best = iou; bi = j; }
        }

        bool eligible = (score > 0.0f) && (hi > lo) && (best > IOU_TH);
        if (eligible) atomicMin(&firstp[bi], p);   // bi in sorted space
    }
    __syncthreads();

    // ---- P5: publish tagged chunk-claims (self-validating atomics) ----
    if (tid < G) {
        int v = firstp[tid];
        unsigned c16 = (v == SENT) ? NOCLAIM : (unsigned)v;   // p < 5000 < 0xFFFF
        atomicExch(&slices[((size_t)b * NSPLIT + s) * G + tid], TAG | c16);
    }
}

extern "C" void kernel_launch(void* const* d_in, const int* in_sizes, int n_in,
                              void* d_out, int out_size, void* d_ws, size_t ws_size,
                              hipStream_t stream) {
    const float* output = (const float*)d_in[0];   // [B,P,6]
    const float* labels = (const float*)d_in[1];   // [B,G,5]

    float* out_stats = (float*)d_out;                       // [B,P,3]
    float* out_tcls  = (float*)d_out + (size_t)B * P * 3;   // [B,G]

    // workspace: tagged claim slices (poison-safe: validated per element)
    unsigned int* slices = (unsigned int*)d_ws;             // B*NSPLIT*G

    dim3 grid(NSPLIT + 1, B);
    fused_kernel<<<grid, NTA, 0, stream>>>(output, labels, slices,
                                           out_stats, out_tcls);
}